// Round 7
// baseline (241.235 us; speedup 1.0000x reference)
//
#include <hip/hip_runtime.h>
#include <math.h>

// VanillaRNN, Wh is (1,H) => scalar recurrence per batch element:
//   s_{t+1} = G(u_t, s_t),  G(u,s) = bh + sum_j wh_j*tanh(wx_j*u + bx_j + s)
// R7 (on R6's coeff-table bicubic scan, which was ISSUE-bound at 345cyc/CU/step
// with 4 waves on only 16 CUs):
//  (a) s-domain [-10,10] (was [-16,16]): s only enters via tanh(c+s), |c|<1.5,
//      saturated for |s|>6 -> edge-clamp is EXACT (G const past the edge).
//      NS=560 rows -> h=0.0358 (finer than R6) -> table 80.6KB.
//  (b) E=2 elements per lane, 32 blocks x 64 threads = 32 CUs, 1 wave each
//      (LDS padded to 96KB to pin 1 block/CU). Two independent interp chains
//      per lane hide each other's DS latency; per-CU issue ~200cyc/step on
//      2x the CUs of R6.

#define SEQ   512
#define BATCH 4096
#define HID   2048
#define NOUT  10
#define KPL   32
#define NS    560           // s-grid rows over [-10,10]
#define NC    8             // u-cells over [-7,7]
#define ROWQ  9             // float4s per s-row (8 cells + 1 pad)

#define S_LOc   (-10.0f)
#define S_H     (20.0f / 559.0f)
#define S_INVH  (559.0f / 20.0f)
#define S_BIAS  (10.0f * S_INVH)    // 279.5
#define NSM1F   559.0f
#define NSM4F   556.0f
#define U_SCALE (8.0f / 14.0f)
#define U_BIAS  4.0f
#define UCMAXF  7.99951f

// ws layout (floats): [0..4096) s_buf ; [4096 ..) coeff table 560*9 float4s
#define WS_SBUF  0
#define WS_TABLE 4096
#define WS_FLOATS_NEEDED (WS_TABLE + NS * ROWQ * 4)

__device__ __forceinline__ float fast_exp2(float v) { return __builtin_amdgcn_exp2f(v); }
__device__ __forceinline__ float fast_rcp(float v)  { return __builtin_amdgcn_rcpf(v); }
__device__ __forceinline__ float fast_tanh(float a) {
    const float C = 2.8853900817779268f;  // 2*log2(e)
    return __builtin_fmaf(-2.0f, fast_rcp(fast_exp2(C * a) + 1.0f), 1.0f);
}
__device__ __forceinline__ float wave_sum(float v) {
#pragma unroll
    for (int m = 1; m < 64; m <<= 1) v += __shfl_xor(v, m, 64);
    return v;
}

// ---------------- K1: coefficient table (560 s-rows x 8 u-cells) ----------------
__global__ __launch_bounds__(256) void k_coef(const float* __restrict__ Wx, const float* __restrict__ bx,
                                              const float* __restrict__ Wh, const float* __restrict__ bh,
                                              float* __restrict__ wf) {
    __shared__ float red[256];
    __shared__ float Gn[32];
    const int k    = blockIdx.x;
    const int node = threadIdx.x & 31;           // 8 cells x 4 Chebyshev nodes
    const int jc   = threadIdx.x >> 5;           // 8 j-chunks of 256
    const int cell = node >> 2, nn = node & 3;
    const float sn = S_LOc + (float)k * S_H;
    const float xi_n = (nn == 0) ? 0.923879533f : (nn == 1) ? 0.382683432f
                     : (nn == 2) ? -0.382683432f : -0.923879533f;
    const float un = (-7.0f + ((float)cell + 0.5f) * 1.75f) + 0.875f * xi_n;
    float p = 0.0f;
    const int j0 = jc * 256;
#pragma unroll 4
    for (int j = j0; j < j0 + 256; ++j)
        p += Wh[j] * fast_tanh(__builtin_fmaf(Wx[j], un, bx[j] + sn));
    red[threadIdx.x] = p;
    __syncthreads();
    if (threadIdx.x < 32) {
        float V = bh[0];
#pragma unroll
        for (int c = 0; c < 8; ++c) V += red[threadIdx.x + 32 * c];
        Gn[threadIdx.x] = __builtin_fmaf(V, S_INVH, S_BIAS);   // normalized next-z
    }
    __syncthreads();
    float4* wq = (float4*)(wf + WS_TABLE);
    if (threadIdx.x < 8) {
        const int c = threadIdx.x;
        float G0 = Gn[4*c+0], G1 = Gn[4*c+1], G2 = Gn[4*c+2], G3 = Gn[4*c+3];
        float d03 = G0 - G3, d12 = G1 - G2;
        float a0 = 0.25f * (G0 + G1 + G2 + G3);
        float a1 = 0.5f * (0.923879533f * d03 + 0.382683432f * d12);
        float a2 = 0.5f * 0.707106781f * (G0 - G1 - G2 + G3);
        float a3 = 0.5f * (0.382683432f * d03 - 0.923879533f * d12);
        // T-basis -> monomial: f = (a0-a2) + (a1-3a3) xi + 2a2 xi^2 + 4a3 xi^3
        wq[k * ROWQ + c] = make_float4(a0 - a2, a1 - 3.0f * a3, 2.0f * a2, 4.0f * a3);
    } else if (threadIdx.x == 8) {
        wq[k * ROWQ + 8] = make_float4(0.f, 0.f, 0.f, 0.f);    // pad (never read)
    }
}

// ---------------- K2: scan — 2 elements per lane, 1 wave per CU, 32 CUs ----------------
__global__ __launch_bounds__(64) void k_scan(const float* __restrict__ x,
                                             const float* __restrict__ bh,
                                             float* __restrict__ wf) {
    __shared__ float4 tabs[6000];                // 96000 B declared -> 1 block/CU
    {
        const float4* src = (const float4*)(wf + WS_TABLE);
        for (int i = threadIdx.x; i < NS * ROWQ; i += 64) tabs[i] = src[i];
    }
    __syncthreads();
    const int b0 = blockIdx.x * 64 + threadIdx.x;      // elems 0..2047
    const int b1 = b0 + 2048;                          // elems 2048..4095

    const float z_init = fminf(fmaxf(__builtin_fmaf(bh[0], S_INVH, S_BIAS), 0.0f), NSM1F);
    float z0 = z_init, z1 = z_init;

    auto step1 = [&](float u, float& z) {
        float uc = fminf(fmaxf(__builtin_fmaf(u, U_SCALE, U_BIAS), 0.0f), UCMAXF);
        float cf = floorf(uc);
        float xi = __builtin_fmaf(2.0f, uc - cf, -1.0f);
        int   ci = (int)cf;
        float zc  = fminf(fmaxf(z, 0.0f), NSM1F);
        float kzf = fminf(fmaxf(floorf(zc) - 1.0f, 0.0f), NSM4F);
        int   kzi = (int)kzf;
        float ts  = zc - kzf;                          // [1,2) interior
        float c0 = ts, c1 = ts - 1.0f, c2 = ts - 2.0f, c3 = ts - 3.0f;
        float n01 = c0 * c1, n23 = c2 * c3;
        float ws0 = c1 * n23 * (-1.0f / 6.0f), ws1 = c0 * n23 * 0.5f;
        float ws2 = n01 * c3 * (-0.5f),        ws3 = n01 * c2 * (1.0f / 6.0f);
        const int base = kzi * ROWQ + ci;
        float4 q0 = tabs[base];
        float4 q1 = tabs[base + ROWQ];
        float4 q2 = tabs[base + 2 * ROWQ];
        float4 q3 = tabs[base + 3 * ROWQ];
        float r0 = __builtin_fmaf(__builtin_fmaf(__builtin_fmaf(q0.w, xi, q0.z), xi, q0.y), xi, q0.x);
        float r1 = __builtin_fmaf(__builtin_fmaf(__builtin_fmaf(q1.w, xi, q1.z), xi, q1.y), xi, q1.x);
        float r2 = __builtin_fmaf(__builtin_fmaf(__builtin_fmaf(q2.w, xi, q2.z), xi, q2.y), xi, q2.x);
        float r3 = __builtin_fmaf(__builtin_fmaf(__builtin_fmaf(q3.w, xi, q3.z), xi, q3.y), xi, q3.x);
        z = __builtin_fmaf(ws0, r0, ws1 * r1) + __builtin_fmaf(ws2, r2, ws3 * r3);
    };

    float cur0[8], cur1[8], nxt0[8], nxt1[8];
#pragma unroll
    for (int i = 0; i < 8; ++i) {
        cur0[i] = x[(size_t)i * BATCH + b0];
        cur1[i] = x[(size_t)i * BATCH + b1];
    }

    for (int c = 0; c < 63; ++c) {                   // steps t = 0..503
#pragma unroll
        for (int i = 0; i < 8; ++i) {                // prefetch chunk c+1
            nxt0[i] = x[(size_t)((c + 1) * 8 + i) * BATCH + b0];
            nxt1[i] = x[(size_t)((c + 1) * 8 + i) * BATCH + b1];
        }
#pragma unroll
        for (int i = 0; i < 8; ++i) {                // two independent chains
            step1(cur0[i], z0);
            step1(cur1[i], z1);
        }
#pragma unroll
        for (int i = 0; i < 8; ++i) { cur0[i] = nxt0[i]; cur1[i] = nxt1[i]; }
    }
#pragma unroll
    for (int i = 0; i < 7; ++i) {                    // tail t = 504..510
        step1(cur0[i], z0);
        step1(cur1[i], z1);
    }

    wf[WS_SBUF + b0] = __builtin_fmaf(z0, S_H, S_LOc);   // denormalize s_511
    wf[WS_SBUF + b1] = __builtin_fmaf(z1, S_H, S_LOc);
}

// ---------------- exact fallback scan (validated R0) ----------------
__global__ __launch_bounds__(256) void rnn_scan_exact(
    const float* __restrict__ x,  const float* __restrict__ Wx,
    const float* __restrict__ bx, const float* __restrict__ Wh,
    const float* __restrict__ bh, float* __restrict__ s_out)
{
    const int lane = threadIdx.x & 63;
    const int wave = threadIdx.x >> 6;
    const int b    = blockIdx.x * 4 + wave;
    const float C = 2.8853900817779268f;
    float wxs[KPL], bxs[KPL], whn[KPL];
    float swh = 0.0f;
#pragma unroll
    for (int k = 0; k < KPL; ++k) {
        const int j = k * 64 + lane;
        const float w = Wh[j];
        wxs[k] = Wx[j] * C; bxs[k] = bx[j] * C; whn[k] = -2.0f * w; swh += w;
    }
    swh = wave_sum(swh);
    const float bh0 = bh[0];
    const float K0  = bh0 + swh;
    float s = bh0, u = x[b];
    for (int t = 0; t < SEQ - 1; ++t) {
        float u_next = x[(size_t)(t + 1) * BATCH + b];
        const float sc = s * C;
        float p = 0.0f;
#pragma unroll
        for (int k = 0; k < KPL; ++k) {
            float arg = __builtin_fmaf(u, wxs[k], bxs[k]) + sc;
            float r   = fast_rcp(fast_exp2(arg) + 1.0f);
            p = __builtin_fmaf(whn[k], r, p);
        }
        s = K0 + wave_sum(p);
        u = u_next;
    }
    if (lane == 0) s_out[b] = s;
}

// ---------------- K3: exact head (validated R0-R6) ----------------
__global__ __launch_bounds__(256) void rnn_head_kernel(
    const float* __restrict__ x,  const float* __restrict__ Wx,
    const float* __restrict__ bx, const float* __restrict__ Wy,
    const float* __restrict__ by, const float* __restrict__ s_in,
    float* __restrict__ out)
{
    const int lane = threadIdx.x & 63;
    const int wave = threadIdx.x >> 6;
    const int b    = blockIdx.x * 4 + wave;
    const float C  = 2.8853900817779268f;
    const float s  = s_in[b];
    const float u  = x[(size_t)(SEQ - 1) * BATCH + b];
    const float sc = s * C;
    float acc[NOUT];
#pragma unroll
    for (int i = 0; i < NOUT; ++i) acc[i] = 0.0f;
#pragma unroll 4
    for (int k = 0; k < KPL; ++k) {
        const int j = k * 64 + lane;
        float arg = __builtin_fmaf(u, Wx[j] * C, bx[j] * C) + sc;
        float r   = fast_rcp(fast_exp2(arg) + 1.0f);
        float th  = __builtin_fmaf(-2.0f, r, 1.0f);
#pragma unroll
        for (int i = 0; i < NOUT; ++i)
            acc[i] = __builtin_fmaf(Wy[i * HID + j], th, acc[i]);
    }
#pragma unroll
    for (int i = 0; i < NOUT; ++i) acc[i] = wave_sum(acc[i]) + by[i];
    float m = acc[0];
#pragma unroll
    for (int i = 1; i < NOUT; ++i) m = fmaxf(m, acc[i]);
    const float L2E = 1.4426950408889634f;
    float ev[NOUT]; float Z = 0.0f;
#pragma unroll
    for (int i = 0; i < NOUT; ++i) { ev[i] = fast_exp2((acc[i] - m) * L2E); Z += ev[i]; }
    const float rz = fast_rcp(Z);
    if (lane == 0) {
#pragma unroll
        for (int i = 0; i < NOUT; ++i) out[(size_t)b * NOUT + i] = ev[i] * rz;
    }
}

extern "C" void kernel_launch(void* const* d_in, const int* in_sizes, int n_in,
                              void* d_out, int out_size, void* d_ws, size_t ws_size,
                              hipStream_t stream)
{
    const float* x  = (const float*)d_in[0];
    const float* Wx = (const float*)d_in[1];
    const float* bx = (const float*)d_in[2];
    const float* Wh = (const float*)d_in[3];
    const float* bh = (const float*)d_in[4];
    const float* Wy = (const float*)d_in[5];
    const float* by = (const float*)d_in[6];
    float* out = (float*)d_out;
    float* wf  = (float*)d_ws;

    if (ws_size >= (size_t)WS_FLOATS_NEEDED * sizeof(float)) {
        k_coef<<<NS, 256, 0, stream>>>(Wx, bx, Wh, bh, wf);
        k_scan<<<32, 64, 0, stream>>>(x, bh, wf);
    } else {
        rnn_scan_exact<<<BATCH / 4, 256, 0, stream>>>(x, Wx, bx, Wh, bh, wf + WS_SBUF);
    }
    rnn_head_kernel<<<BATCH / 4, 256, 0, stream>>>(x, Wx, bx, Wy, by, wf + WS_SBUF, out);
}

// Round 9
// 143.992 us; speedup vs baseline: 1.6753x; 1.6753x over previous
//
#include <hip/hip_runtime.h>
#include <math.h>

// VanillaRNN, Wh is (1,H) => scalar recurrence per batch element:
//   s_{t+1} = G(u_t, s_t),  G(u,s) = bh + sum_j wh_j*tanh(wx_j*u + bx_j + s)
// R9: 2-segment parallel-in-time speculation with PIECEWISE-CUBIC combine.
//  R8's 4-node global cubic over [-10,10] measured 0.098 output error
//  (calibrating |Phi''''| ~ 2e-3). Piecewise cubic over N uniform nodes scales
//  that by 0.0234*h^4/52 (geometry only, |Phi''''| cancels):
//   - Tier A (ws>=240KB): 14 nodes, h=1.54 -> ~2.5e-4. 240 blocks, 3 launches.
//   - Tier B (ws>=80KB, guaranteed by R8 run): 9 nodes, h=2.5 -> ~1.7e-3.
//     5 node bufs borrow d_out; separate combine kernel drains them into ws
//     BEFORE head writes d_out (kills the cross-block d_out race). 4 launches.
//  Scan blocks stay R6's proven shape (256 thr = 4 waves/CU, ~345 cyc/step);
//  LDS padded to 83.2KB to pin 1 block/CU. Serial wall 256 steps ~ 37us.

#define SEQ   512
#define BATCH 4096
#define HID   2048
#define NOUT  10
#define KPL   32
#define NS    560           // s-grid rows over [-10,10]
#define ROWQ  9             // float4s per s-row (8 u-cells + 1 pad)

#define S_LOc   (-10.0f)
#define S_H     (20.0f / 559.0f)
#define S_INVH  (559.0f / 20.0f)
#define S_BIAS  (10.0f * S_INVH)
#define NSM1F   559.0f
#define NSM4F   556.0f
#define U_SCALE (8.0f / 14.0f)
#define U_BIAS  4.0f
#define UCMAXF  7.99951f

#define TABLE_FLOATS (NS * ROWQ * 4)       // 20160 floats (in d_out scratch)
// Tier A: ws = z255[4096] + 14 node bufs  -> 61440 floats (245760 B)
// Tier B: ws = z255[4096] + 4 node bufs   -> 20480 floats (81920 B);
//         node bufs 0..4 in d_out at [20160 .. 20160+5*4096=40640) <= 40960
#define WSA_FLOATS (4096 + 14 * 4096)
#define WSB_FLOATS (4096 + 4 * 4096)
#define DZ14 43.0f          // 559/13 node spacing (z-units), exact
#define DZ9  69.875f        // 559/8, exact

__device__ __forceinline__ float fast_exp2(float v) { return __builtin_amdgcn_exp2f(v); }
__device__ __forceinline__ float fast_rcp(float v)  { return __builtin_amdgcn_rcpf(v); }
__device__ __forceinline__ float fast_tanh(float a) {
    const float C = 2.8853900817779268f;  // 2*log2(e)
    return __builtin_fmaf(-2.0f, fast_rcp(fast_exp2(C * a) + 1.0f), 1.0f);
}
__device__ __forceinline__ float wave_sum(float v) {
#pragma unroll
    for (int m = 1; m < 64; m <<= 1) v += __shfl_xor(v, m, 64);
    return v;
}
// piecewise-cubic Lagrange combine: z' = Phi(z255) from nn node values
__device__ __forceinline__ float combine_eval(float z255, int nn, float dz,
                                              const float* baseA, const float* baseB,
                                              int split, int b) {
    float p = z255 / dz;                               // [0, nn-1]
    int   c = min(max((int)floorf(p) - 1, 0), nn - 4);
    float t = p - (float)c;
    float a0 = t, a1 = t - 1.0f, a2 = t - 2.0f, a3 = t - 3.0f;
    float m01 = a0 * a1, m23 = a2 * a3;
    float w0 = a1 * m23 * (-1.0f / 6.0f), w1 = a0 * m23 * 0.5f;
    float w2 = m01 * a3 * (-0.5f),        w3 = m01 * a2 * (1.0f / 6.0f);
    float y[4];
#pragma unroll
    for (int i = 0; i < 4; ++i) {
        int n = c + i;
        const float* ptr = (n < split) ? (baseA + (size_t)n * 4096)
                                       : (baseB + (size_t)(n - split) * 4096);
        y[i] = ptr[b];
    }
    return __builtin_fmaf(w0, y[0], w1 * y[1]) + __builtin_fmaf(w2, y[2], w3 * y[3]);
}

// ---------------- K1: coefficient table (560 s-rows x 8 u-cells) -> d_out ----------------
__global__ __launch_bounds__(256) void k_coef(const float* __restrict__ Wx, const float* __restrict__ bx,
                                              const float* __restrict__ Wh, const float* __restrict__ bh,
                                              float* __restrict__ tab_g) {
    __shared__ float red[256];
    __shared__ float Gn[32];
    const int k    = blockIdx.x;
    const int node = threadIdx.x & 31;           // 8 cells x 4 Chebyshev nodes
    const int jc   = threadIdx.x >> 5;           // 8 j-chunks of 256
    const int cell = node >> 2, nn = node & 3;
    const float sn = S_LOc + (float)k * S_H;
    const float xi_n = (nn == 0) ? 0.923879533f : (nn == 1) ? 0.382683432f
                     : (nn == 2) ? -0.382683432f : -0.923879533f;
    const float un = (-7.0f + ((float)cell + 0.5f) * 1.75f) + 0.875f * xi_n;
    float p = 0.0f;
    const int j0 = jc * 256;
#pragma unroll 4
    for (int j = j0; j < j0 + 256; ++j)
        p += Wh[j] * fast_tanh(__builtin_fmaf(Wx[j], un, bx[j] + sn));
    red[threadIdx.x] = p;
    __syncthreads();
    if (threadIdx.x < 32) {
        float V = bh[0];
#pragma unroll
        for (int c = 0; c < 8; ++c) V += red[threadIdx.x + 32 * c];
        Gn[threadIdx.x] = __builtin_fmaf(V, S_INVH, S_BIAS);   // normalized next-z
    }
    __syncthreads();
    float4* wq = (float4*)tab_g;
    if (threadIdx.x < 8) {
        const int c = threadIdx.x;
        float G0 = Gn[4*c+0], G1 = Gn[4*c+1], G2 = Gn[4*c+2], G3 = Gn[4*c+3];
        float d03 = G0 - G3, d12 = G1 - G2;
        float a0 = 0.25f * (G0 + G1 + G2 + G3);
        float a1 = 0.5f * (0.923879533f * d03 + 0.382683432f * d12);
        float a2 = 0.5f * 0.707106781f * (G0 - G1 - G2 + G3);
        float a3 = 0.5f * (0.382683432f * d03 - 0.923879533f * d12);
        wq[k * ROWQ + c] = make_float4(a0 - a2, a1 - 3.0f * a3, 2.0f * a2, 4.0f * a3);
    } else if (threadIdx.x == 8) {
        wq[k * ROWQ + 8] = make_float4(0.f, 0.f, 0.f, 0.f);    // pad (never read)
    }
}

// ---------------- K2: 2-segment scan (R6 shape: 4 waves/CU, 1 block/CU) ----------------
// blk<16: seg0 (t=0..254 from true init) -> z255 = ws[0..4096)
// else:   seg1 (t=255..510 from node state node*dz) -> node buf (split A/B)
__global__ __launch_bounds__(256) void k_scan_seg(const float* __restrict__ x,
                                                  const float* __restrict__ bh,
                                                  const float* __restrict__ tab_g,
                                                  float* __restrict__ z255,
                                                  float* __restrict__ baseA,
                                                  float* __restrict__ baseB,
                                                  int split, float dz) {
    __shared__ float4 tabs[5200];                // 83200 B -> pins 1 block/CU
    {
        const float4* src = (const float4*)tab_g;
        for (int i = threadIdx.x; i < NS * ROWQ; i += 256) tabs[i] = src[i];
    }
    __syncthreads();
    const int blk = blockIdx.x;
    const int seg  = (blk < 16) ? 0 : 1;
    const int node = seg ? (blk - 16) >> 4 : 0;
    const int eb   = seg ? (blk - 16) & 15 : blk;
    const int b    = eb * 256 + threadIdx.x;

    const int t0     = seg ? 255 : 0;
    const int nsteps = seg ? 256 : 255;

    float z = seg ? (float)node * dz
                  : fminf(fmaxf(__builtin_fmaf(bh[0], S_INVH, S_BIAS), 0.0f), NSM1F);

    auto step1 = [&](float u) {
        float uc = fminf(fmaxf(__builtin_fmaf(u, U_SCALE, U_BIAS), 0.0f), UCMAXF);
        float cf = floorf(uc);
        float xi = __builtin_fmaf(2.0f, uc - cf, -1.0f);
        int   ci = (int)cf;
        float zc  = fminf(fmaxf(z, 0.0f), NSM1F);
        float kzf = fminf(fmaxf(floorf(zc) - 1.0f, 0.0f), NSM4F);
        int   kzi = (int)kzf;
        float ts  = zc - kzf;
        float c0 = ts, c1 = ts - 1.0f, c2 = ts - 2.0f, c3 = ts - 3.0f;
        float n01 = c0 * c1, n23 = c2 * c3;
        float ws0 = c1 * n23 * (-1.0f / 6.0f), ws1 = c0 * n23 * 0.5f;
        float ws2 = n01 * c3 * (-0.5f),        ws3 = n01 * c2 * (1.0f / 6.0f);
        const int base = kzi * ROWQ + ci;
        float4 q0 = tabs[base];
        float4 q1 = tabs[base + ROWQ];
        float4 q2 = tabs[base + 2 * ROWQ];
        float4 q3 = tabs[base + 3 * ROWQ];
        float r0 = __builtin_fmaf(__builtin_fmaf(__builtin_fmaf(q0.w, xi, q0.z), xi, q0.y), xi, q0.x);
        float r1 = __builtin_fmaf(__builtin_fmaf(__builtin_fmaf(q1.w, xi, q1.z), xi, q1.y), xi, q1.x);
        float r2 = __builtin_fmaf(__builtin_fmaf(__builtin_fmaf(q2.w, xi, q2.z), xi, q2.y), xi, q2.x);
        float r3 = __builtin_fmaf(__builtin_fmaf(__builtin_fmaf(q3.w, xi, q3.z), xi, q3.y), xi, q3.x);
        z = __builtin_fmaf(ws0, r0, ws1 * r1) + __builtin_fmaf(ws2, r2, ws3 * r3);
    };

    float cur[8], nxt[8];
#pragma unroll
    for (int i = 0; i < 8; ++i)
        cur[i] = x[(size_t)min(t0 + i, SEQ - 1) * BATCH + b];

    const int full = nsteps >> 3, tail = nsteps & 7;
    for (int c = 0; c < full; ++c) {
        const int nb = t0 + (c + 1) * 8;
#pragma unroll
        for (int i = 0; i < 8; ++i)
            nxt[i] = x[(size_t)min(nb + i, SEQ - 1) * BATCH + b];
#pragma unroll
        for (int i = 0; i < 8; ++i) step1(cur[i]);
#pragma unroll
        for (int i = 0; i < 8; ++i) cur[i] = nxt[i];
    }
    for (int i = 0; i < tail; ++i) step1(cur[i]);    // wave-uniform tail (<=7)

    if (seg == 0) z255[b] = z;
    else {
        float* p = (node < split) ? (baseA + (size_t)node * 4096)
                                  : (baseB + (size_t)(node - split) * 4096);
        p[b] = z;
    }
}

// ---------------- Tier B combine: drain node bufs (d_out+ws) -> s in ws ----------------
__global__ __launch_bounds__(256) void k_combine(const float* __restrict__ baseA,
                                                 const float* __restrict__ baseB,
                                                 int split, int nn, float dz,
                                                 float* __restrict__ zs) {
    const int b = blockIdx.x * 256 + threadIdx.x;
    float zz = combine_eval(zs[b], nn, dz, baseA, baseB, split, b);
    zs[b] = __builtin_fmaf(zz, S_H, S_LOc);          // denormalized s_511
}

// ---------------- Tier A: fused combine (all node bufs in ws) + head ----------------
__global__ __launch_bounds__(256) void head_combine_A(
    const float* __restrict__ x,  const float* __restrict__ Wx,
    const float* __restrict__ bx, const float* __restrict__ Wy,
    const float* __restrict__ by, const float* __restrict__ ws,
    float* __restrict__ out)
{
    const int lane = threadIdx.x & 63;
    const int wave = threadIdx.x >> 6;
    const int b    = blockIdx.x * 4 + wave;

    float zz = combine_eval(ws[b], 14, DZ14, ws + 4096, ws + 4096, 14, b);
    const float s = __builtin_fmaf(zz, S_H, S_LOc);

    const float C  = 2.8853900817779268f;
    const float u  = x[(size_t)(SEQ - 1) * BATCH + b];
    const float sc = s * C;
    float acc[NOUT];
#pragma unroll
    for (int i = 0; i < NOUT; ++i) acc[i] = 0.0f;
#pragma unroll 4
    for (int k = 0; k < KPL; ++k) {
        const int j = k * 64 + lane;
        float arg = __builtin_fmaf(u, Wx[j] * C, bx[j] * C) + sc;
        float r   = fast_rcp(fast_exp2(arg) + 1.0f);
        float th  = __builtin_fmaf(-2.0f, r, 1.0f);
#pragma unroll
        for (int i = 0; i < NOUT; ++i)
            acc[i] = __builtin_fmaf(Wy[i * HID + j], th, acc[i]);
    }
#pragma unroll
    for (int i = 0; i < NOUT; ++i) acc[i] = wave_sum(acc[i]) + by[i];
    float m = acc[0];
#pragma unroll
    for (int i = 1; i < NOUT; ++i) m = fmaxf(m, acc[i]);
    const float L2E = 1.4426950408889634f;
    float ev[NOUT]; float Z = 0.0f;
#pragma unroll
    for (int i = 0; i < NOUT; ++i) { ev[i] = fast_exp2((acc[i] - m) * L2E); Z += ev[i]; }
    const float rz = fast_rcp(Z);
    if (lane == 0) {
#pragma unroll
        for (int i = 0; i < NOUT; ++i) out[(size_t)b * NOUT + i] = ev[i] * rz;
    }
}

// ---------------- exact scan + head (validated R0; also tier-B head) ----------------
__global__ __launch_bounds__(256) void rnn_scan_exact(
    const float* __restrict__ x,  const float* __restrict__ Wx,
    const float* __restrict__ bx, const float* __restrict__ Wh,
    const float* __restrict__ bh, float* __restrict__ s_out)
{
    const int lane = threadIdx.x & 63;
    const int wave = threadIdx.x >> 6;
    const int b    = blockIdx.x * 4 + wave;
    const float C = 2.8853900817779268f;
    float wxs[KPL], bxs[KPL], whn[KPL];
    float swh = 0.0f;
#pragma unroll
    for (int k = 0; k < KPL; ++k) {
        const int j = k * 64 + lane;
        const float w = Wh[j];
        wxs[k] = Wx[j] * C; bxs[k] = bx[j] * C; whn[k] = -2.0f * w; swh += w;
    }
    swh = wave_sum(swh);
    const float bh0 = bh[0];
    const float K0  = bh0 + swh;
    float s = bh0, u = x[b];
    for (int t = 0; t < SEQ - 1; ++t) {
        float u_next = x[(size_t)(t + 1) * BATCH + b];
        const float sc = s * C;
        float p = 0.0f;
#pragma unroll
        for (int k = 0; k < KPL; ++k) {
            float arg = __builtin_fmaf(u, wxs[k], bxs[k]) + sc;
            float r   = fast_rcp(fast_exp2(arg) + 1.0f);
            p = __builtin_fmaf(whn[k], r, p);
        }
        s = K0 + wave_sum(p);
        u = u_next;
    }
    if (lane == 0) s_out[b] = s;
}

__global__ __launch_bounds__(256) void rnn_head_exact(
    const float* __restrict__ x,  const float* __restrict__ Wx,
    const float* __restrict__ bx, const float* __restrict__ Wy,
    const float* __restrict__ by, const float* __restrict__ s_in,
    float* __restrict__ out)
{
    const int lane = threadIdx.x & 63;
    const int wave = threadIdx.x >> 6;
    const int b    = blockIdx.x * 4 + wave;
    const float C  = 2.8853900817779268f;
    const float s  = s_in[b];
    const float u  = x[(size_t)(SEQ - 1) * BATCH + b];
    const float sc = s * C;
    float acc[NOUT];
#pragma unroll
    for (int i = 0; i < NOUT; ++i) acc[i] = 0.0f;
#pragma unroll 4
    for (int k = 0; k < KPL; ++k) {
        const int j = k * 64 + lane;
        float arg = __builtin_fmaf(u, Wx[j] * C, bx[j] * C) + sc;
        float r   = fast_rcp(fast_exp2(arg) + 1.0f);
        float th  = __builtin_fmaf(-2.0f, r, 1.0f);
#pragma unroll
        for (int i = 0; i < NOUT; ++i)
            acc[i] = __builtin_fmaf(Wy[i * HID + j], th, acc[i]);
    }
#pragma unroll
    for (int i = 0; i < NOUT; ++i) acc[i] = wave_sum(acc[i]) + by[i];
    float m = acc[0];
#pragma unroll
    for (int i = 1; i < NOUT; ++i) m = fmaxf(m, acc[i]);
    const float L2E = 1.4426950408889634f;
    float ev[NOUT]; float Z = 0.0f;
#pragma unroll
    for (int i = 0; i < NOUT; ++i) { ev[i] = fast_exp2((acc[i] - m) * L2E); Z += ev[i]; }
    const float rz = fast_rcp(Z);
    if (lane == 0) {
#pragma unroll
        for (int i = 0; i < NOUT; ++i) out[(size_t)b * NOUT + i] = ev[i] * rz;
    }
}

extern "C" void kernel_launch(void* const* d_in, const int* in_sizes, int n_in,
                              void* d_out, int out_size, void* d_ws, size_t ws_size,
                              hipStream_t stream)
{
    const float* x  = (const float*)d_in[0];
    const float* Wx = (const float*)d_in[1];
    const float* bx = (const float*)d_in[2];
    const float* Wh = (const float*)d_in[3];
    const float* bh = (const float*)d_in[4];
    const float* Wy = (const float*)d_in[5];
    const float* by = (const float*)d_in[6];
    float* out = (float*)d_out;
    float* wf  = (float*)d_ws;

    if (ws_size >= (size_t)WSA_FLOATS * sizeof(float)) {
        // Tier A: 14 nodes, all node bufs in ws; 3 launches
        k_coef<<<NS, 256, 0, stream>>>(Wx, bx, Wh, bh, out);
        k_scan_seg<<<16 + 14 * 16, 256, 0, stream>>>(x, bh, out, wf,
                                                     wf + 4096, wf + 4096, 14, DZ14);
        head_combine_A<<<BATCH / 4, 256, 0, stream>>>(x, Wx, bx, Wy, by, wf, out);
    } else if (ws_size >= (size_t)WSB_FLOATS * sizeof(float)) {
        // Tier B: 9 nodes (5 bufs borrow d_out, drained by k_combine before head)
        k_coef<<<NS, 256, 0, stream>>>(Wx, bx, Wh, bh, out);
        k_scan_seg<<<16 + 9 * 16, 256, 0, stream>>>(x, bh, out, wf,
                                                    out + TABLE_FLOATS, wf + 4096, 5, DZ9);
        k_combine<<<16, 256, 0, stream>>>(out + TABLE_FLOATS, wf + 4096, 5, 9, DZ9, wf);
        rnn_head_exact<<<BATCH / 4, 256, 0, stream>>>(x, Wx, bx, Wy, by, wf, out);
    } else {
        rnn_scan_exact<<<BATCH / 4, 256, 0, stream>>>(x, Wx, bx, Wh, bh, wf);
        rnn_head_exact<<<BATCH / 4, 256, 0, stream>>>(x, Wx, bx, Wy, by, wf, out);
    }
}